// Round 18
// baseline (270.717 us; speedup 1.0000x reference)
//
#include <hip/hip_runtime.h>
#include <hip/hip_bf16.h>

// HypoNerf fused MLP on MI355X (gfx950). R18: tile double-pipeline.
//  Plateau diagnosis: co-resident blocks are PHASE-LOCKED (identical code,
//  same start) -> each phase binds one pipe while others idle; MfmaUtil 42%
//  == exact MFMA demand. Fix: split the 64-row tile into independent halves
//  A (rows 0-31) and B (rows 32-63), each in its own 16KB LDS buffer, and
//  time-shift them by one segment:
//    [KloopA(li) || epiB(li-1)] -> bar -> [KloopB(li) || epiA(li)] -> bar
//  Every segment mixes MFMA+VMEM+DS-read with VALU+DS-write -> epilogue
//  hides in the MFMA shadow; bar_raw is GONE (writes target the buffer
//  nobody read this segment; bar_lgkm drains reads + publishes writes).
//  Cost: each half streams layer weights separately (2x VMEM, L2-resident,
//  ~46 B/cy/CU < 56 budget). Regs: acc 64 + wf 16 + af 8 + 2 ptrs ~= 110
//  < 128 -> 4 waves/SIMD kept. wf is a single shared buffer reloaded after
//  use, alternating fpA/fpB streams; cross-segment reload gets a full
//  segment of latency cover. Final overrun read lands in biases (harmless).

#define H 256
#define MT 64
#define PE_NF 60

typedef __attribute__((ext_vector_type(8))) short s16x8;   // 8 bf16
typedef __attribute__((ext_vector_type(4))) float f32x4;   // MFMA acc

#define BATCH_BYTES (size_t)589824   // 576KB: 64KB (l0) + 4*128KB
#define BATCH_ELEMS (size_t)294912

static __device__ __forceinline__ unsigned short f2bf(float v) {
  unsigned int u = __float_as_uint(v);
  return (unsigned short)((u + 0x7FFFu + ((u >> 16) & 1u)) >> 16);
}
// swizzled 16B-chunk index within a 256-elem (32-chunk) row
static __device__ __forceinline__ int hswz(int row, int chunk) {
  return (chunk & ~7) | ((chunk ^ row) & 7);
}

static __device__ __forceinline__ void bar_lgkm() {
  asm volatile("s_waitcnt lgkmcnt(0)\n\ts_barrier" ::: "memory");
}

// ---------------------------------------------------------------------------
// Prep: wb (fp32, [K+1][H], last row bias) -> per-batch contiguous
// fragment-packed bf16 stream (R14 format).  Within a layer, frag id =
// kt*16 + (n>>4); within frag: idx = (kgrp*16 + (n&15))*8 + (k&7).
// Layer li starts at elem offset {0,32768,98304,163840,229376}[li].
// ---------------------------------------------------------------------------
__global__ __launch_bounds__(256) void prep_weights(
    const float* __restrict__ wb0, const float* __restrict__ wb1,
    const float* __restrict__ wb2, const float* __restrict__ wb3,
    const float* __restrict__ wb4,
    unsigned short* __restrict__ wpk, float* __restrict__ biases) {
  int z = blockIdx.z;
  int li = z >> 4, b = z & 15;
  int k0 = blockIdx.x * 32;
  int n0 = blockIdx.y * 32;
  int Ks;
  const float* src;
  unsigned short* dst;
  if (li == 0) {
    Ks = 120;
    if (k0 >= 128) return;
    src = wb0 + (size_t)b * 121 * H;
    dst = wpk + b * BATCH_ELEMS;
  } else {
    Ks = 256;
    const float* srcs[4] = {wb1, wb2, wb3, wb4};
    src = srcs[li - 1] + (size_t)b * 257 * H;
    dst = wpk + b * BATCH_ELEMS + 32768 + (size_t)(li - 1) * 65536;
  }
  __shared__ float tile[32][33];
  int t = threadIdx.x;
  int tx = t & 31, ty = t >> 5;
#pragma unroll
  for (int i = 0; i < 4; ++i) {
    int k = k0 + ty + i * 8;
    tile[ty + i * 8][tx] = (k < Ks) ? src[(size_t)k * H + n0 + tx] : 0.f;
  }
  if (k0 == 0 && ty == 0)
    biases[((size_t)li * 16 + b) * H + n0 + tx] = src[(size_t)Ks * H + n0 + tx];
  __syncthreads();
  if (t < 128) {
    int nn = t & 31, kg = t >> 5;
    int n = n0 + nn;
    int kt = k0 >> 5;
    union { unsigned short us[8]; s16x8 v; } pk;
#pragma unroll
    for (int j = 0; j < 8; ++j) pk.us[j] = f2bf(tile[kg * 8 + j][nn]);
    *(s16x8*)&dst[(size_t)(kt * 16 + (n >> 4)) * 512 + (kg * 16 + (n & 15)) * 8] = pk.v;
  }
}

// ---------------------------------------------------------------------------
// K-loop over one 32-row half. Wave wc: cols [wc*64,+64), acc[2][4].
// hb = this half's LDS buffer (bytes). On entry wf holds this half's kt0;
// fp -> this half's kt1. Exits with wf = other stream's kt0 (from fpo,
// issued with a full segment of cover) and fp/fpo advanced.
// A-op (weights): lane holds W^T[wc*64+ct*16+rlane][kt*32+kgrp*8 ..+7]
// B-op (h):       lane holds h_half[rt*16+rlane][same k]
// C: m(half) = rt*16+(l&15), n = wc*64+ct*16+(l>>4)*4+reg
// ---------------------------------------------------------------------------
template <int NKT>
static __device__ __forceinline__ void kloop_seg(
    const char*& fp, const char*& fpo, const float* __restrict__ bl,
    const char* hb, const unsigned be, const unsigned bo,
    const int wc, const int kgrp, s16x8 (&wf)[4], f32x4 (&acc)[2][4]) {
#pragma unroll
  for (int ct = 0; ct < 4; ++ct) {
    f32x4 bini = *(const f32x4*)(bl + wc * 64 + ct * 16 + kgrp * 4);
    acc[0][ct] = bini;
    acc[1][ct] = bini;
  }
#pragma unroll 2
  for (int kt = 0; kt < NKT - 1; ++kt) {
    s16x8 af[2];
    const unsigned base = ((kt & 1) ? bo : be) + (kt >> 1) * 128;
    af[0] = *(const s16x8*)(hb + base);
    af[1] = *(const s16x8*)(hb + base + 8192);
    __builtin_amdgcn_s_setprio(1);
#pragma unroll
    for (int rt = 0; rt < 2; ++rt)
#pragma unroll
      for (int ct = 0; ct < 4; ++ct)
        acc[rt][ct] = __builtin_amdgcn_mfma_f32_16x16x32_bf16(
            wf[ct], af[rt], acc[rt][ct], 0, 0, 0);
    __builtin_amdgcn_s_setprio(0);
#pragma unroll
    for (int c = 0; c < 4; ++c)
      wf[c] = *(const s16x8*)(fp + c * 1024);
    fp += 16384;
  }
  // last kt: reload targets the OTHER stream's kt0 (covered by epi + bar)
  {
    s16x8 af[2];
    const unsigned base = (((NKT - 1) & 1) ? bo : be) + ((NKT - 1) >> 1) * 128;
    af[0] = *(const s16x8*)(hb + base);
    af[1] = *(const s16x8*)(hb + base + 8192);
    __builtin_amdgcn_s_setprio(1);
#pragma unroll
    for (int rt = 0; rt < 2; ++rt)
#pragma unroll
      for (int ct = 0; ct < 4; ++ct)
        acc[rt][ct] = __builtin_amdgcn_mfma_f32_16x16x32_bf16(
            wf[ct], af[rt], acc[rt][ct], 0, 0, 0);
    __builtin_amdgcn_s_setprio(0);
#pragma unroll
    for (int c = 0; c < 4; ++c)
      wf[c] = *(const s16x8*)(fpo + c * 1024);
    fpo += 16384;
  }
}

// epilogue of one half: ReLU + pack 4 bf16 -> b64 store into hb
static __device__ __forceinline__ void epi_half(
    f32x4 (&acc)[2][4], char* hb, const int rlane, const int kgrp,
    const int wc) {
  const int sub = (kgrp & 1) * 4;
  const int cbase = wc * 8 + (kgrp >> 1);
#pragma unroll
  for (int rt = 0; rt < 2; ++rt) {
    const int m = rt * 16 + rlane;      // row within half (0..31)
    const int rowb = m * 512;           // bytes
#pragma unroll
    for (int ct = 0; ct < 4; ++ct) {
      const int cs = hswz(m, cbase + ct * 2);
      float v0 = fmaxf(acc[rt][ct][0], 0.f);
      float v1 = fmaxf(acc[rt][ct][1], 0.f);
      float v2 = fmaxf(acc[rt][ct][2], 0.f);
      float v3 = fmaxf(acc[rt][ct][3], 0.f);
      union { __hip_bfloat162 h2[2]; uint2 u; } pk;
      pk.h2[0] = __float22bfloat162_rn(float2{v0, v1});
      pk.h2[1] = __float22bfloat162_rn(float2{v2, v3});
      *(uint2*)(hb + rowb + cs * 16 + sub * 2) = pk.u;
    }
  }
}

// folded projection of one half: psum[wc*64 + half*32 + row]
static __device__ __forceinline__ void proj_half(
    f32x4 (&acc)[2][4], const float* __restrict__ wout_s, float* psum,
    const int l, const int wc, const int kgrp, const int half) {
  float p[2];
#pragma unroll
  for (int rt = 0; rt < 2; ++rt) {
    float s = 0.f;
#pragma unroll
    for (int ct = 0; ct < 4; ++ct) {
      f32x4 wv = *(const f32x4*)(wout_s + wc * 64 + ct * 16 + kgrp * 4);
#pragma unroll
      for (int g = 0; g < 4; ++g)
        s += fmaxf(acc[rt][ct][g], 0.f) * wv[g];
    }
    s += __shfl_xor(s, 16);
    s += __shfl_xor(s, 32);
    p[rt] = s;
  }
  if (l < 16) {
    psum[wc * 64 + half * 32 + l]      = p[0];
    psum[wc * 64 + half * 32 + 16 + l] = p[1];
  }
}

// ---------------------------------------------------------------------------
__global__ __launch_bounds__(256, 4) void hyponerf_main(
    const float* __restrict__ x, const float* __restrict__ rfreq,
    const float* __restrict__ wbout, const unsigned short* __restrict__ wpk,
    const float* __restrict__ biases, float* __restrict__ out) {
  __shared__ __align__(16) unsigned short h_s[MT * 256];  // 2 x 16KB halves
  __shared__ float fr_s[PE_NF * 3];
  __shared__ float x_s[MT * 3];
  __shared__ float wout_s[H + 1];
  __shared__ float psum[4 * 64];

  // XCD-aware swizzle: 4096 blocks, 8 XCDs -> contiguous batches per XCD
  int bid = blockIdx.x;
  int logical = (bid & 7) * 512 + (bid >> 3);
  int b  = logical >> 8;
  int mt = logical & 255;

  int t = threadIdx.x;
  int wc = t >> 6, l = t & 63;
  int rlane = l & 15;
  int kgrp  = l >> 4;

  char* hA = (char*)h_s;            // rows 0-31
  char* hB = (char*)h_s + 16384;    // rows 32-63
  // parity DS bases (offsets within a half buffer): hswz(r,c+8)=hswz(r,c)+8
  const unsigned be = rlane * 512 + ((kgrp ^ (rlane & 7)) & 7) * 16;
  const unsigned bo = rlane * 512 + (((4 + kgrp) ^ (rlane & 7)) & 7) * 16;

  // two running weight-stream pointers (A and B consume the blob separately)
  const char* fpA = (const char*)wpk + b * BATCH_BYTES
                  + (size_t)wc * 4096 + (size_t)l * 16;
  const char* fpB = fpA;

  // issue A's layer0 kt0 frags NOW; latency hides under staging + PE
  s16x8 wf[4];
#pragma unroll
  for (int c = 0; c < 4; ++c) wf[c] = *(const s16x8*)(fpA + c * 1024);
  fpA += 16384;

  const float* xg = x + ((size_t)b * 16384 + (size_t)mt * MT) * 3;
  for (int i = t; i < MT * 3; i += 256) x_s[i] = xg[i];
  for (int i = t; i < PE_NF * 3; i += 256) fr_s[i] = rfreq[i] * 20.0f;
  for (int i = t; i < H + 1; i += 256) wout_s[i] = wbout[(size_t)b * (H + 1) + i];
  bar_lgkm();   // staging visible; vmcnt NOT drained

  // ---- Gaussian PE, chunk-owned b128 stores: thread (r = t>>2, q = t&3)
  //   rows 0-31 -> hA, rows 32-63 -> hB
  {
    int r = t >> 2;
    int q = t & 3;
    float x0 = x_s[r * 3 + 0], x1 = x_s[r * 3 + 1], x2 = x_s[r * 3 + 2];
    char* hb = (r < 32) ? hA : hB;
    int rowb = (r & 31) * 512;
#pragma unroll
    for (int cc = 0; cc < 4; ++cc) {
      int ch = q * 4 + cc;
      union { unsigned short us[8]; s16x8 v; } pk;
#pragma unroll
      for (int j = 0; j < 8; ++j) {
        int n = ch * 8 + j;
        float v = 0.f;
        if (n < 60) {
          float kv = x0 * fr_s[n * 3] + x1 * fr_s[n * 3 + 1] + x2 * fr_s[n * 3 + 2];
          v = __sinf(kv);
        } else if (n < 120) {
          int f = n - 60;
          float kv = x0 * fr_s[f * 3] + x1 * fr_s[f * 3 + 1] + x2 * fr_s[f * 3 + 2];
          v = __cosf(kv);
        }
        pk.us[j] = f2bf(v);
      }
      *(s16x8*)(hb + rowb + hswz(r & 31, ch) * 16) = pk.v;
    }
  }
  bar_lgkm();   // PE writes visible; A's kt0 frags still in flight

  const float* bb = biases + (size_t)b * H;
  f32x4 accA[2][4], accB[2][4];

  // ---- layer 0 (K=128)
  kloop_seg<4>(fpA, fpB, bb, hA, be, bo, wc, kgrp, wf, accA);
  bar_lgkm();
  kloop_seg<4>(fpB, fpA, bb, hB, be, bo, wc, kgrp, wf, accB);
  epi_half(accA, hA, rlane, kgrp, wc);
  bar_lgkm();

  // ---- layers 1..3 (steady double-pipeline)
#pragma unroll 1
  for (int li = 1; li < 4; ++li) {
    const float* bl = bb + (size_t)li * 16 * H;
    kloop_seg<8>(fpA, fpB, bl, hA, be, bo, wc, kgrp, wf, accA);
    epi_half(accB, hB, rlane, kgrp, wc);     // epiB(li-1)
    bar_lgkm();
    kloop_seg<8>(fpB, fpA, bl, hB, be, bo, wc, kgrp, wf, accB);
    epi_half(accA, hA, rlane, kgrp, wc);     // epiA(li)
    bar_lgkm();
  }

  // ---- layer 4 (+ folded projection; no h writes)
  {
    const float* bl = bb + (size_t)4 * 16 * H;
    kloop_seg<8>(fpA, fpB, bl, hA, be, bo, wc, kgrp, wf, accA);
    epi_half(accB, hB, rlane, kgrp, wc);     // epiB(3)
    bar_lgkm();
    kloop_seg<8>(fpB, fpA, bl, hB, be, bo, wc, kgrp, wf, accB);
    // (last reload overruns into biases region: harmless)
    proj_half(accA, wout_s, psum, l, wc, kgrp, 0);
    proj_half(accB, wout_s, psum, l, wc, kgrp, 1);
    bar_lgkm();
  }

  // ---- gather: out[r] = sum_wc psum[wc][r] + bias_out
  if (t < MT) {
    float s = psum[t] + psum[64 + t] + psum[128 + t] + psum[192 + t];
    out[(size_t)b * 16384 + (size_t)mt * MT + t] = s + wout_s[H];
  }
}

// ---------------------------------------------------------------------------
extern "C" void kernel_launch(void* const* d_in, const int* in_sizes, int n_in,
                              void* d_out, int out_size, void* d_ws, size_t ws_size,
                              hipStream_t stream) {
  const float* x     = (const float*)d_in[0];
  const float* wb0   = (const float*)d_in[1];
  const float* wb1   = (const float*)d_in[2];
  const float* wb2   = (const float*)d_in[3];
  const float* wb3   = (const float*)d_in[4];
  const float* wb4   = (const float*)d_in[5];
  const float* wbout = (const float*)d_in[6];
  const float* rfreq = (const float*)d_in[7];
  float* out = (float*)d_out;

  char* ws = (char*)d_ws;
  unsigned short* wpk = (unsigned short*)ws;                    // 16 x 576KB
  float* biases = (float*)(ws + 16 * BATCH_BYTES);              // [5][16][256]

  prep_weights<<<dim3(8, 8, 80), 256, 0, stream>>>(wb0, wb1, wb2, wb3, wb4,
                                                   wpk, biases);
  hyponerf_main<<<dim3(4096), 256, 0, stream>>>(x, rfreq, wbout, wpk,
                                                biases, out);
}

// Round 19
// 163.324 us; speedup vs baseline: 1.6576x; 1.6576x over previous
//
#include <hip/hip_runtime.h>
#include <hip/hip_bf16.h>

// HypoNerf fused MLP on MI355X (gfx950). R19 = R10 (best measured, 165.7us)
// + R14's contiguous weight blob (single running stream pointer, no branch).
//  Session conclusion territory: R6/R9/R10/R11/R12/R17/R18 bracket a robust
//  plateau at 166+-4us (~933 TF). At R10: MfmaUtil == MFMA demand (74us
//  busy), no pipe saturated, conflicts at b128 structural minimum, and any
//  added pipelining state spills (acc floor = 64 f32). This round restores
//  the best point with one strictly-free simplification.
//  Structure: MT=64, 4096 blocks, 4 waves col-split, 3 waves/SIMD,
//  16x16x32 MFMA, wf[2][4]+af[2][4] double-buffers, fragment-packed
//  contiguous weight stream (+16KB/kt across all layers; end-of-chain
//  overrun reads biases region -- allocated, harmless), parity DS bases,
//  folded final projection, raw barriers (no vmcnt drain), XCD swizzle.

#define H 256
#define MT 64
#define PE_NF 60

typedef __attribute__((ext_vector_type(8))) short s16x8;   // 8 bf16
typedef __attribute__((ext_vector_type(4))) float f32x4;   // MFMA acc

#define BATCH_BYTES (size_t)589824   // 576KB: 64KB (l0) + 4*128KB
#define BATCH_ELEMS (size_t)294912

static __device__ __forceinline__ unsigned short f2bf(float v) {
  unsigned int u = __float_as_uint(v);
  return (unsigned short)((u + 0x7FFFu + ((u >> 16) & 1u)) >> 16);
}
// swizzled 16B-chunk index within a 256-elem (32-chunk) row
static __device__ __forceinline__ int hswz(int row, int chunk) {
  return (chunk & ~7) | ((chunk ^ row) & 7);
}

static __device__ __forceinline__ void bar_raw() {
  asm volatile("s_barrier" ::: "memory");
}
static __device__ __forceinline__ void bar_lgkm() {
  asm volatile("s_waitcnt lgkmcnt(0)\n\ts_barrier" ::: "memory");
}

// ---------------------------------------------------------------------------
// Prep: wb (fp32, [K+1][H], last row bias) -> per-batch contiguous
// fragment-packed bf16 stream.  Within a layer, frag id = kt*16 + (n>>4);
// within frag: idx = (kgrp*16 + (n&15))*8 + (k&7).  Layer li starts at
// elem offset {0, 32768, 98304, 163840, 229376}[li] in the batch blob.
// ---------------------------------------------------------------------------
__global__ __launch_bounds__(256) void prep_weights(
    const float* __restrict__ wb0, const float* __restrict__ wb1,
    const float* __restrict__ wb2, const float* __restrict__ wb3,
    const float* __restrict__ wb4,
    unsigned short* __restrict__ wpk, float* __restrict__ biases) {
  int z = blockIdx.z;
  int li = z >> 4, b = z & 15;
  int k0 = blockIdx.x * 32;
  int n0 = blockIdx.y * 32;
  int Ks;
  const float* src;
  unsigned short* dst;
  if (li == 0) {
    Ks = 120;
    if (k0 >= 128) return;
    src = wb0 + (size_t)b * 121 * H;
    dst = wpk + b * BATCH_ELEMS;
  } else {
    Ks = 256;
    const float* srcs[4] = {wb1, wb2, wb3, wb4};
    src = srcs[li - 1] + (size_t)b * 257 * H;
    dst = wpk + b * BATCH_ELEMS + 32768 + (size_t)(li - 1) * 65536;
  }
  __shared__ float tile[32][33];
  int t = threadIdx.x;
  int tx = t & 31, ty = t >> 5;
#pragma unroll
  for (int i = 0; i < 4; ++i) {
    int k = k0 + ty + i * 8;
    tile[ty + i * 8][tx] = (k < Ks) ? src[(size_t)k * H + n0 + tx] : 0.f;
  }
  if (k0 == 0 && ty == 0)
    biases[((size_t)li * 16 + b) * H + n0 + tx] = src[(size_t)Ks * H + n0 + tx];
  __syncthreads();
  if (t < 128) {
    int nn = t & 31, kg = t >> 5;
    int n = n0 + nn;
    int kt = k0 >> 5;
    union { unsigned short us[8]; s16x8 v; } pk;
#pragma unroll
    for (int j = 0; j < 8; ++j) pk.us[j] = f2bf(tile[kg * 8 + j][nn]);
    *(s16x8*)&dst[(size_t)(kt * 16 + (n >> 4)) * 512 + (kg * 16 + (n & 15)) * 8] = pk.v;
  }
}

// ---------------------------------------------------------------------------
// One fused Linear+ReLU layer. Wave wc: all 64 rows x cols [wc*64,+64).
// acc[4][4]. fp = running stream pointer (incl. wc*4096 + l*16), pointing
// at the NEXT kt's 4 frags; advances +16KB/kt continuously across layers.
// On entry wf[0] holds this layer's kt0 frags; on exit wf[0] holds the next
// layer's kt0 (the single end-of-chain overrun reads biases: harmless).
// A-op (weights): lane holds W^T[wc*64+ct*16+rlane][kt*32+kgrp*8 ..+7]
// B-op (h):       lane holds h[rt*16+rlane][same k]
// C: m = rt*16+(l&15), n = wc*64+ct*16+(l>>4)*4+reg
// ---------------------------------------------------------------------------
template <int NKT, bool LAST>
static __device__ __forceinline__ void mlp_layer(
    const char*& fp, const float* __restrict__ bl,
    unsigned short* __restrict__ h_s,
    const int rlane, const int kgrp, const int wc, const int l,
    s16x8 (&wf)[2][4], const float* wout_r, float* psum) {
  static_assert((NKT & 1) == 0, "ping-pong parity needs even NKT");
  f32x4 acc[4][4];
#pragma unroll
  for (int ct = 0; ct < 4; ++ct) {
    f32x4 bini = *(const f32x4*)(bl + wc * 64 + ct * 16 + kgrp * 4);
#pragma unroll
    for (int rt = 0; rt < 4; ++rt) acc[rt][ct] = bini;
  }

  // h ds_read bases: parity trick hswz(r, c+8) = hswz(r, c) + 8
  const char* hb = (const char*)h_s;
  const unsigned be = rlane * 512 + hswz(rlane, kgrp) * 16;
  const unsigned bo = rlane * 512 + hswz(rlane, 4 + kgrp) * 16;

  // h-fragment double buffer: kt0
  s16x8 af[2][4];
#pragma unroll
  for (int rt = 0; rt < 4; ++rt)
    af[0][rt] = *(const s16x8*)(hb + be + rt * 8192);

#pragma unroll
  for (int kt = 0; kt < NKT; ++kt) {
    // prefetch kt+1 weight frags from the contiguous stream (at the layer
    // boundary this IS the next layer's kt0; end-of-chain overrun: biases)
#pragma unroll
    for (int c = 0; c < 4; ++c)
      wf[(kt + 1) & 1][c] = *(const s16x8*)(fp + c * 1024);
    fp += 16384;
    if (kt + 1 < NKT) {
      const unsigned base = (((kt + 1) & 1) ? bo : be) + ((kt + 1) >> 1) * 128;
#pragma unroll
      for (int rt = 0; rt < 4; ++rt)
        af[(kt + 1) & 1][rt] = *(const s16x8*)(hb + base + rt * 8192);
    }
    __builtin_amdgcn_s_setprio(1);
#pragma unroll
    for (int rt = 0; rt < 4; ++rt)
#pragma unroll
      for (int ct = 0; ct < 4; ++ct)
        acc[rt][ct] = __builtin_amdgcn_mfma_f32_16x16x32_bf16(
            wf[kt & 1][ct], af[kt & 1][rt], acc[rt][ct], 0, 0, 0);
    __builtin_amdgcn_s_setprio(0);
  }

  if constexpr (LAST) {
    // folded projection: p[rt] = sum_n relu(h[m][n]) * wout[n]
    float p[4];
#pragma unroll
    for (int rt = 0; rt < 4; ++rt) {
      float s = 0.f;
#pragma unroll
      for (int ct = 0; ct < 4; ++ct)
#pragma unroll
        for (int g = 0; g < 4; ++g)
          s += fmaxf(acc[rt][ct][g], 0.f) * wout_r[ct * 4 + g];
      s += __shfl_xor(s, 16);
      s += __shfl_xor(s, 32);
      p[rt] = s;
    }
    if (l < 16) {
#pragma unroll
      for (int rt = 0; rt < 4; ++rt)
        psum[wc * 64 + rt * 16 + l] = p[rt];
    }
  } else {
    bar_raw();   // h reads consumed by MFMAs; vmcnt NOT drained
    // epilogue: ReLU + pack 4 bf16 -> b64 store  h[m][n0..n0+3]
    const int sub = (kgrp & 1) * 4;
    const int cbase = wc * 8 + (kgrp >> 1);
#pragma unroll
    for (int rt = 0; rt < 4; ++rt) {
      const int m = rt * 16 + rlane;
      const int rowb = m * 256;
#pragma unroll
      for (int ct = 0; ct < 4; ++ct) {
        const int cs = hswz(m, cbase + ct * 2);
        float v0 = fmaxf(acc[rt][ct][0], 0.f);
        float v1 = fmaxf(acc[rt][ct][1], 0.f);
        float v2 = fmaxf(acc[rt][ct][2], 0.f);
        float v3 = fmaxf(acc[rt][ct][3], 0.f);
        union { __hip_bfloat162 h2[2]; uint2 u; } pk;
        pk.h2[0] = __float22bfloat162_rn(float2{v0, v1});
        pk.h2[1] = __float22bfloat162_rn(float2{v2, v3});
        *(uint2*)&h_s[rowb + cs * 8 + sub] = pk.u;
      }
    }
    bar_lgkm();  // DS writes visible; vmcnt untouched
  }
}

// ---------------------------------------------------------------------------
__global__ __launch_bounds__(256, 3) void hyponerf_main(
    const float* __restrict__ x, const float* __restrict__ rfreq,
    const float* __restrict__ wbout, const unsigned short* __restrict__ wpk,
    const float* __restrict__ biases, float* __restrict__ out) {
  __shared__ __align__(16) unsigned short h_s[MT * 256];  // 32768 B
  __shared__ float fr_s[PE_NF * 3];
  __shared__ float x_s[MT * 3];
  __shared__ float psum[4 * 64];

  // XCD-aware swizzle: 4096 blocks, 8 XCDs -> contiguous batches per XCD
  int bid = blockIdx.x;
  int logical = (bid & 7) * 512 + (bid >> 3);
  int b  = logical >> 8;
  int mt = logical & 255;

  int t = threadIdx.x;
  int wc = t >> 6, l = t & 63;
  int rlane = l & 15;
  int kgrp  = l >> 4;

  // single running weight-stream pointer (batch blob + wave-col + lane)
  const char* fp = (const char*)wpk + b * BATCH_BYTES
                 + (size_t)wc * 4096 + (size_t)l * 16;

  // issue layer0 kt0 frags NOW; latency hides under staging + PE
  s16x8 wf[2][4];
#pragma unroll
  for (int c = 0; c < 4; ++c) wf[0][c] = *(const s16x8*)(fp + c * 1024);
  fp += 16384;

  // preload wout for the folded final projection (scalar loads; lane's
  // cols = wc*64 + ct*16 + kgrp*4 + g)
  float wout_r[16];
  {
    const float* wob = wbout + (size_t)b * (H + 1) + wc * 64 + kgrp * 4;
#pragma unroll
    for (int ct = 0; ct < 4; ++ct)
#pragma unroll
      for (int g = 0; g < 4; ++g) wout_r[ct * 4 + g] = wob[ct * 16 + g];
  }
  const float wout_bias = wbout[(size_t)b * (H + 1) + H];

  const float* xg = x + ((size_t)b * 16384 + (size_t)mt * MT) * 3;
  for (int i = t; i < MT * 3; i += 256) x_s[i] = xg[i];
  for (int i = t; i < PE_NF * 3; i += 256) fr_s[i] = rfreq[i] * 20.0f;
  bar_lgkm();   // staging visible; vmcnt NOT drained

  // ---- Gaussian PE, chunk-owned b128 stores: thread (r = t>>2, q = t&3)
  //   covers n in [q*32, q*32+32): n<60 sin, 60..119 cos(n-60), 120..127 0.
  {
    int r = t >> 2;
    int q = t & 3;
    float x0 = x_s[r * 3 + 0], x1 = x_s[r * 3 + 1], x2 = x_s[r * 3 + 2];
    int rowb = r * 256;
#pragma unroll
    for (int cc = 0; cc < 4; ++cc) {
      int ch = q * 4 + cc;
      union { unsigned short us[8]; s16x8 v; } pk;
#pragma unroll
      for (int j = 0; j < 8; ++j) {
        int n = ch * 8 + j;
        float v = 0.f;
        if (n < 60) {
          float kv = x0 * fr_s[n * 3] + x1 * fr_s[n * 3 + 1] + x2 * fr_s[n * 3 + 2];
          v = __sinf(kv);
        } else if (n < 120) {
          int f = n - 60;
          float kv = x0 * fr_s[f * 3] + x1 * fr_s[f * 3 + 1] + x2 * fr_s[f * 3 + 2];
          v = __cosf(kv);
        }
        pk.us[j] = f2bf(v);
      }
      *(s16x8*)&h_s[rowb + hswz(r, ch) * 8] = pk.v;
    }
  }
  bar_lgkm();   // PE writes visible; layer0 frags still in flight

  // ---- 5 fused Linear+ReLU layers (fp streams through all of them)
  const float* bb = biases + (size_t)b * H;
  mlp_layer<4, false>(fp, bb + 0 * 16 * H, h_s, rlane, kgrp, wc, l, wf,
                      wout_r, psum);
  mlp_layer<8, false>(fp, bb + 1 * 16 * H, h_s, rlane, kgrp, wc, l, wf,
                      wout_r, psum);
  mlp_layer<8, false>(fp, bb + 2 * 16 * H, h_s, rlane, kgrp, wc, l, wf,
                      wout_r, psum);
  mlp_layer<8, false>(fp, bb + 3 * 16 * H, h_s, rlane, kgrp, wc, l, wf,
                      wout_r, psum);
  mlp_layer<8, true >(fp, bb + 4 * 16 * H, h_s, rlane, kgrp, wc, l, wf,
                      wout_r, psum);

  // ---- gather: out[r] = sum_wc psum[wc][r] + bias_out
  bar_lgkm();
  if (t < MT) {
    float s = psum[t] + psum[64 + t] + psum[128 + t] + psum[192 + t];
    out[(size_t)b * 16384 + (size_t)mt * MT + t] = s + wout_bias;
  }
}

// ---------------------------------------------------------------------------
extern "C" void kernel_launch(void* const* d_in, const int* in_sizes, int n_in,
                              void* d_out, int out_size, void* d_ws, size_t ws_size,
                              hipStream_t stream) {
  const float* x     = (const float*)d_in[0];
  const float* wb0   = (const float*)d_in[1];
  const float* wb1   = (const float*)d_in[2];
  const float* wb2   = (const float*)d_in[3];
  const float* wb3   = (const float*)d_in[4];
  const float* wb4   = (const float*)d_in[5];
  const float* wbout = (const float*)d_in[6];
  const float* rfreq = (const float*)d_in[7];
  float* out = (float*)d_out;

  char* ws = (char*)d_ws;
  unsigned short* wpk = (unsigned short*)ws;                    // 16 x 576KB
  float* biases = (float*)(ws + 16 * BATCH_BYTES);              // [5][16][256]

  prep_weights<<<dim3(8, 8, 80), 256, 0, stream>>>(wb0, wb1, wb2, wb3, wb4,
                                                   wpk, biases);
  hyponerf_main<<<dim3(4096), 256, 0, stream>>>(x, rfreq, wbout, wpk,
                                                biases, out);
}